// Round 14
// baseline (144.738 us; speedup 1.0000x reference)
//
#include <hip/hip_runtime.h>

#define LRELU_ALPHA 0.2f

constexpr int NN    = 4096;
constexpr int FIN   = 512;
constexpr int NH    = 8;
constexpr int FOUT  = 64;
constexpr int NFLAT = NH * FOUT; // 512
constexpr float LOG2E = 1.4426950408889634f;

typedef __attribute__((ext_vector_type(8))) __bf16 bf16x8;
typedef __attribute__((ext_vector_type(4))) __bf16 bf16x4;
typedef __attribute__((ext_vector_type(4))) float f32x4;
typedef __attribute__((ext_vector_type(16))) float f32x16;

__device__ __forceinline__ unsigned bitsmear(unsigned mk, int e) {
    return (unsigned)(((int)(mk << (31 - e))) >> 31);   // bit e -> 0 / 0xFFFFFFFF
}

// ================= k_prep: W -> wtsw (bf16, pre-swizzled for k_main's gload_lds) =========
__global__ __launch_bounds__(256) void k_prep(const float* __restrict__ W,
                                              __bf16* __restrict__ wtsw) {
    __shared__ float tile[64][68];
    const int bid = blockIdx.x;
    const int t = threadIdx.x;
    const int kt = bid >> 3;
    const int fb = (bid & 7) * 64;
    {
        const int kk = t >> 2, cq = (t & 3) * 16;
        #pragma unroll
        for (int i = 0; i < 4; ++i)
            *(float4*)&tile[kk][cq + i * 4] =
                *(const float4*)&W[(size_t)(kt * 64 + kk) * NFLAT + fb + cq + i * 4];
    }
    __syncthreads();
    const int fl = t >> 2;
    #pragma unroll
    for (int c = 0; c < 2; ++c) {
        int gs = (t & 3) * 2 + c;
        int g  = gs ^ (fl & 7);
        bf16x8 o;
        #pragma unroll
        for (int jo = 0; jo < 8; ++jo) o[jo] = (__bf16)tile[g * 8 + jo][fl];
        *(bf16x8*)&wtsw[((size_t)(kt * NFLAT + fb + fl)) * 64 + gs * 8] = o;
    }
}

// ================= k_main: gemm(->whtB32 fragment order, fused f12) + bitmask =============
// whtB32 per (h,jt) 8KB block: [jg(0..7)][f(0..63)][8 j's] bf16.
__global__ __launch_bounds__(256) void k_main(const float* __restrict__ x,
                                              const int* __restrict__ adj,
                                              const float* __restrict__ av,
                                              const __bf16* __restrict__ wtsw,
                                              __bf16* __restrict__ whtB32,
                                              float* __restrict__ f1T,
                                              float* __restrict__ f2pn,
                                              unsigned long long* __restrict__ bmT) {
    __shared__ alignas(16) __bf16 Bs[2][64 * 64];
    const int bid = blockIdx.x;
    const int t = threadIdx.x;
    if (bid < 512) {
        // ---- Wh = bf16(x) @ bf16(W) via 16x16x32 MFMA ----
        const int wv = t >> 6, l = t & 63;
        const int jt = bid & 63, h = bid >> 6;
        const int bm = jt * 64, bn = h * 64;
        const int lm = l & 15, lk = l >> 4;
        const int swB = (lm & 7) << 4;

        f32x4 acc[4] = {};
        auto stageB = [&](int kt, int bb) {
            #pragma unroll
            for (int kq = 0; kq < 2; ++kq) {
                int u = t + kq * 256;
                __builtin_amdgcn_global_load_lds(
                    (const __attribute__((address_space(1))) void*)(wtsw + (size_t)(kt * NFLAT + bn) * 64 + u * 8),
                    (__attribute__((address_space(3))) void*)((char*)&Bs[bb][0] + u * 16), 16, 0, 0);
            }
        };

        stageB(0, 0);
        const float* xrow = &x[(size_t)(bm + wv * 16 + lm) * FIN + lk * 8];
        for (int kt = 0; kt < 8; ++kt) {
            bf16x8 aF[2];
            #pragma unroll
            for (int ks = 0; ks < 2; ++ks) {
                float4 u0 = *(const float4*)&xrow[kt * 64 + ks * 32];
                float4 u1 = *(const float4*)&xrow[kt * 64 + ks * 32 + 4];
                bf16x8 af;
                af[0] = (__bf16)u0.x; af[1] = (__bf16)u0.y; af[2] = (__bf16)u0.z; af[3] = (__bf16)u0.w;
                af[4] = (__bf16)u1.x; af[5] = (__bf16)u1.y; af[6] = (__bf16)u1.z; af[7] = (__bf16)u1.w;
                aF[ks] = af;
            }
            __syncthreads();
            if (kt < 7) stageB(kt + 1, (kt + 1) & 1);
            const char* wb = (const char*)&Bs[kt & 1][0];
            #pragma unroll
            for (int q = 0; q < 4; ++q) {
                #pragma unroll
                for (int ks = 0; ks < 2; ++ks) {
                    bf16x8 bF = *(const bf16x8*)(wb + (((q * 16 + lm) * 128 + lk * 16 + ks * 64) ^ swB));
                    acc[q] = __builtin_amdgcn_mfma_f32_16x16x32_bf16(aF[ks], bF, acc[q], 0, 0, 0);
                }
            }
        }
        // ---- epilogue 1: whtB32 fragment-ordered store ----
        {
            char* blk = (char*)whtB32 + ((size_t)(h * 64 + jt) << 13);  // 8KB per (h,jt)
            const int jg = wv * 2 + (lk >> 1);
            const int j7o = (lk & 1) * 8;
            #pragma unroll
            for (int q = 0; q < 4; ++q) {
                const int f = q * 16 + lm;
                bf16x4 o;
                #pragma unroll
                for (int r = 0; r < 4; ++r) o[r] = (__bf16)acc[q][r];
                *(bf16x4*)(blk + (jg * 64 + f) * 16 + j7o) = o;
            }
        }
        // ---- epilogue 2: fused f12 ----
        float av1[4], av2[4];
        #pragma unroll
        for (int q = 0; q < 4; ++q) {
            av1[q] = av[q * 16 + lm];
            av2[q] = av[64 + q * 16 + lm];
        }
        float s1[4] = {}, s2[4] = {};
        #pragma unroll
        for (int q = 0; q < 4; ++q)
            #pragma unroll
            for (int r = 0; r < 4; ++r) {
                s1[r] = fmaf(acc[q][r], av1[q], s1[r]);
                s2[r] = fmaf(acc[q][r], av2[q], s2[r]);
            }
        #pragma unroll
        for (int off = 1; off < 16; off <<= 1) {
            #pragma unroll
            for (int r = 0; r < 4; ++r) {
                s1[r] += __shfl_xor(s1[r], off);
                s2[r] += __shfl_xor(s2[r], off);
            }
        }
        if (lm == 0) {
            #pragma unroll
            for (int r = 0; r < 4; ++r) {
                const int io = bm + wv * 16 + lk * 4 + r;
                f1T[h * NN + io] = s1[r] * LOG2E;
                float s2l = s2[r] * LOG2E;
                float2 v = make_float2(exp2f(s2l), exp2f(LRELU_ALPHA * s2l));
                *(float2*)&f2pn[2 * ((size_t)h * NN + io)] = v;
            }
        }
    } else {
        // ---- bitmask pack: adj -> bmT[jt*NN + i] ----
        const size_t base = (size_t)(bid - 512) * 16384;
        for (int it = 0; it < 64; ++it) {
            size_t idx = base + (size_t)it * 256 + t;
            int v = adj[idx];
            unsigned long long b = __ballot(v > 0);
            if ((t & 63) == 0) {
                int i = (int)(idx >> 12);
                int jt = (int)((idx >> 6) & 63);
                bmT[(size_t)jt * NN + i] = b;
            }
        }
    }
}

// ================= k_attn: per-wave 2x4KB half-tile dbuf, counted vmcnt, 4 blocks/CU =======
// Block = 32 i x 1 head; wave wv owns j-tiles [wv*16, wv*16+16); zero atomics.
__global__ __launch_bounds__(256, 4) void k_attn(const unsigned long long* __restrict__ bmT,
                                                 const __bf16* __restrict__ whtB32,
                                                 const float* __restrict__ f1T,
                                                 const float* __restrict__ f2pn,
                                                 float* __restrict__ oacc) {
    __shared__ alignas(16) char Ws[4][2][4096];    // per-wave half-tile dbuf (32KB total)
    __shared__ float Lsh[4][64];                   // row-sum partials (1KB)

    const int t   = threadIdx.x;
    const int wv  = t >> 6, l = t & 63;
    const int gi0 = blockIdx.x * 32;
    const int h   = blockIdx.y;
    const int jt0 = wv * 16;                       // per-wave j-chunk (16 tiles = 32 halves)

    const int lc = l & 31, hi = l >> 5;
    const int iA = gi0 + lc;
    const float f1v = f1T[h * NN + iA];
    const float E1p = exp2f(f1v);
    const float E1n = exp2f(LRELU_ALPHA * f1v);

    f32x16 acc0 = {}, acc1 = {};
    float lpart = 0.f;

    // rolling pointers (advanced per HALF: gsrc +4096, fptr +256; mptr per tile)
    const char* gsrc = (const char*)whtB32 + ((size_t)(h * 64 + jt0) << 13) + l * 16;
    const char* fptr = (const char*)f2pn + ((size_t)h * NN + (size_t)jt0 * 64) * 8 + hi * 64;
    const unsigned long long* mptr = bmT + (size_t)jt0 * NN + iA;
    char* const wsA = &Ws[wv][0][0];
    char* const wsB = &Ws[wv][1][0];
    const int dsoff = (hi << 10) | (lc << 4);

    auto stage = [&](const char* src, char* dstbase) {      // 4KB half-tile
        #pragma unroll
        for (int k = 0; k < 4; ++k)
            __builtin_amdgcn_global_load_lds(
                (const __attribute__((address_space(1))) void*)(src + k * 1024),
                (__attribute__((address_space(3))) void*)(dstbase + l * 16 + k * 1024), 16, 0, 0);
    };
    auto loadF2 = [&](float4* F, const char* fp) {          // 8 float4 = 2 js steps
        #pragma unroll
        for (int js = 0; js < 2; ++js)
            #pragma unroll
            for (int u = 0; u < 4; ++u)
                F[js * 4 + u] = *(const float4*)(fp + js * 128 + u * 16);
    };
    // compute one half H (0/1) of a tile from buffer wsb + f-regs F + tile mask m
    auto compute = [&](const char* wsb, const float4* F, unsigned long long m, int H) {
        const char* bp = wsb + dsoff;
        #pragma unroll
        for (int jsl = 0; jsl < 2; ++jsl) {
            unsigned mk = (unsigned)(m >> (16 * (2 * H + jsl) + 8 * hi));
            bf16x8 aF;
            #pragma unroll
            for (int u = 0; u < 4; ++u) {
                float4 vv = F[jsl * 4 + u];
                float a0 = fmaxf(E1p * vv.x, E1n * vv.y);
                float a1 = fmaxf(E1p * vv.z, E1n * vv.w);
                a0 = __uint_as_float(__float_as_uint(a0) & bitsmear(mk, 2 * u));
                a1 = __uint_as_float(__float_as_uint(a1) & bitsmear(mk, 2 * u + 1));
                lpart += a0 + a1;
                aF[2 * u]     = (__bf16)a0;
                aF[2 * u + 1] = (__bf16)a1;
            }
            bf16x8 bF0 = *(const bf16x8*)(bp + jsl * 2048);
            bf16x8 bF1 = *(const bf16x8*)(bp + jsl * 2048 + 512);
            __builtin_amdgcn_s_setprio(1);
            acc0 = __builtin_amdgcn_mfma_f32_32x32x16_bf16(aF, bF0, acc0, 0, 0, 0);
            acc1 = __builtin_amdgcn_mfma_f32_32x32x16_bf16(aF, bF1, acc1, 0, 0, 0);
            __builtin_amdgcn_s_setprio(0);
        }
    };

    float4 fA[8], fB[8];
    unsigned long long mA_, mB_;

    // prologue: tile0 half0 -> {wsA, fA}, m(tile0) -> mA_   (13 loads)
    stage(gsrc, wsA);
    __builtin_amdgcn_sched_barrier(0);
    loadF2(fA, fptr);
    mA_ = mptr[0];
    __builtin_amdgcn_sched_barrier(0);
    gsrc += 4096; fptr += 256;

    // NOTE: final-iteration prefetches overrun into adjacent d_ws regions (valid memory,
    // values never consumed).
    #pragma unroll 1
    for (int tt = 0; tt < 16; tt += 2) {
        // -- tile tt, half0: consume {wsA,fA,mA_}; prefetch h1 -> {wsB,fB} (12) --
        stage(gsrc, wsB);
        __builtin_amdgcn_sched_barrier(0);
        loadF2(fB, fptr);
        __builtin_amdgcn_sched_barrier(0);
        gsrc += 4096; fptr += 256;
        asm volatile("s_waitcnt vmcnt(12)" ::: "memory");
        __builtin_amdgcn_sched_barrier(0);
        compute(wsA, fA, mA_, 0);
        // -- tile tt, half1: consume {wsB,fB,mA_}; prefetch tile+1 h0 -> {wsA,fA,mB_} (13) --
        stage(gsrc, wsA);
        __builtin_amdgcn_sched_barrier(0);
        loadF2(fA, fptr);
        mB_ = mptr[NN];
        __builtin_amdgcn_sched_barrier(0);
        gsrc += 4096; fptr += 256;
        asm volatile("s_waitcnt vmcnt(13)" ::: "memory");
        __builtin_amdgcn_sched_barrier(0);
        compute(wsB, fB, mA_, 1);
        // -- tile tt+1, half0: consume {wsA,fA,mB_}; prefetch h1 -> {wsB,fB} (12) --
        stage(gsrc, wsB);
        __builtin_amdgcn_sched_barrier(0);
        loadF2(fB, fptr);
        __builtin_amdgcn_sched_barrier(0);
        gsrc += 4096; fptr += 256;
        asm volatile("s_waitcnt vmcnt(12)" ::: "memory");
        __builtin_amdgcn_sched_barrier(0);
        compute(wsA, fA, mB_, 0);
        // -- tile tt+1, half1: consume {wsB,fB,mB_}; prefetch tile+2 h0 -> {wsA,fA,mA_} (13) --
        stage(gsrc, wsA);
        __builtin_amdgcn_sched_barrier(0);
        loadF2(fA, fptr);
        mA_ = mptr[2 * NN];
        __builtin_amdgcn_sched_barrier(0);
        gsrc += 4096; fptr += 256;
        asm volatile("s_waitcnt vmcnt(13)" ::: "memory");
        __builtin_amdgcn_sched_barrier(0);
        compute(wsB, fB, mB_, 1);
        mptr += 2 * NN;
    }

    // drain outstanding prefetches before reusing buffers for the reduction
    asm volatile("s_waitcnt vmcnt(0)" ::: "memory");
    __builtin_amdgcn_sched_barrier(0);

    // ---- write partials into own (dead) staging buffers: Rp spans both halves (8KB) ----
    {
        float* Rp = (float*)wsA;                   // 32 rows x 64 cols f32 = 8KB (Ws[wv][0..1])
        #pragma unroll
        for (int reg = 0; reg < 16; ++reg) {
            const int row = (reg & 3) + 8 * (reg >> 2) + 4 * hi;
            Rp[row * 64 + lc]      = acc0[reg];
            Rp[row * 64 + 32 + lc] = acc1[reg];
        }
        Lsh[wv][hi * 32 + lc] = lpart;
    }
    __syncthreads();

    // ---- cross-wave reduce + normalize + plain store (no atomics) ----
    {
        const int row = t >> 3, c0 = (t & 7) * 8;
        float ls = 0.f;
        #pragma unroll
        for (int w2 = 0; w2 < 4; ++w2)
            ls += Lsh[w2][row] + Lsh[w2][32 + row];
        const float inv = 1.0f / (ls * (float)NH);
        f32x4 s0 = {}, s1 = {};
        #pragma unroll
        for (int w2 = 0; w2 < 4; ++w2) {
            const float* Rp2 = (const float*)&Ws[w2][0][0];
            s0 += *(const f32x4*)&Rp2[row * 64 + c0];
            s1 += *(const f32x4*)&Rp2[row * 64 + c0 + 4];
        }
        float* dst = &oacc[(size_t)(gi0 + row) * NFLAT + h * 64 + c0];
        *(f32x4*)dst       = s0 * inv;
        *(f32x4*)(dst + 4) = s1 * inv;
    }
}

// ================= k_norm: head-sum only (oacc already normalized) =================
__global__ __launch_bounds__(256) void k_norm(const float* __restrict__ oacc,
                                              float* __restrict__ out) {
    int t = blockIdx.x * 256 + threadIdx.x;
    int i = t >> 4, fq = (t & 15) * 4;
    f32x4 s = {};
    #pragma unroll
    for (int h = 0; h < 8; ++h)
        s += *(const f32x4*)&oacc[(size_t)i * NFLAT + h * 64 + fq];
    *(f32x4*)&out[(size_t)i * FOUT + fq] = s;
}

extern "C" void kernel_launch(void* const* d_in, const int* in_sizes, int n_in,
                              void* d_out, int out_size, void* d_ws, size_t ws_size,
                              hipStream_t stream) {
    const float* x   = (const float*)d_in[0];
    const int*   adj = (const int*)d_in[1];
    const float* W   = (const float*)d_in[2];
    const float* a   = (const float*)d_in[3];
    float* out = (float*)d_out;

    char* ws = (char*)d_ws;
    float* oacc = (float*)ws;           ws += (size_t)NN * NFLAT * 4;   // 8 MiB
    float* f1T = (float*)ws;            ws += (size_t)NH * NN * 4;      // 128 KiB
    float* f2pn = (float*)ws;           ws += (size_t)NH * NN * 8;      // 256 KiB
    __bf16* whtB32 = (__bf16*)ws;       ws += (size_t)NFLAT * NN * 2;   // 4 MiB
    unsigned long long* bmT = (unsigned long long*)ws; ws += (size_t)NN * NN / 8; // 2 MiB
    __bf16* wtsw = (__bf16*)ws;         ws += (size_t)FIN * NFLAT * 2;  // 512 KiB

    k_prep<<<64, 256, 0, stream>>>(W, wtsw);
    k_main<<<1536, 256, 0, stream>>>(x, adj, a, wtsw, whtB32, f1T, f2pn, bmT);
    k_attn<<<dim3(NN / 32, NH), 256, 0, stream>>>(bmT, whtB32, f1T, f2pn, oacc);
    k_norm<<<NN * FOUT / 4 / 256, 256, 0, stream>>>(oacc, out);
}

// Round 15
// 102.392 us; speedup vs baseline: 1.4136x; 1.4136x over previous
//
#include <hip/hip_runtime.h>

#define LRELU_ALPHA 0.2f

constexpr int NN    = 4096;
constexpr int FIN   = 512;
constexpr int NH    = 8;
constexpr int FOUT  = 64;
constexpr int NFLAT = NH * FOUT; // 512
constexpr float LOG2E = 1.4426950408889634f;

typedef __attribute__((ext_vector_type(8))) __bf16 bf16x8;
typedef __attribute__((ext_vector_type(4))) __bf16 bf16x4;
typedef __attribute__((ext_vector_type(4))) float f32x4;
typedef __attribute__((ext_vector_type(16))) float f32x16;

__device__ __forceinline__ unsigned bitsmear(unsigned mk, int e) {
    return (unsigned)(((int)(mk << (31 - e))) >> 31);   // bit e -> 0 / 0xFFFFFFFF
}

// ================= k_prep: W -> wtsw (bf16, pre-swizzled for k_main's gload_lds) =========
__global__ __launch_bounds__(256) void k_prep(const float* __restrict__ W,
                                              __bf16* __restrict__ wtsw) {
    __shared__ float tile[64][68];
    const int bid = blockIdx.x;
    const int t = threadIdx.x;
    const int kt = bid >> 3;
    const int fb = (bid & 7) * 64;
    {
        const int kk = t >> 2, cq = (t & 3) * 16;
        #pragma unroll
        for (int i = 0; i < 4; ++i)
            *(float4*)&tile[kk][cq + i * 4] =
                *(const float4*)&W[(size_t)(kt * 64 + kk) * NFLAT + fb + cq + i * 4];
    }
    __syncthreads();
    const int fl = t >> 2;
    #pragma unroll
    for (int c = 0; c < 2; ++c) {
        int gs = (t & 3) * 2 + c;
        int g  = gs ^ (fl & 7);
        bf16x8 o;
        #pragma unroll
        for (int jo = 0; jo < 8; ++jo) o[jo] = (__bf16)tile[g * 8 + jo][fl];
        *(bf16x8*)&wtsw[((size_t)(kt * NFLAT + fb + fl)) * 64 + gs * 8] = o;
    }
}

// ================= k_main: gemm(->whtB32 fragment order, fused f12) + bitmask =============
// whtB32 per (h,jt) 8KB block: [jg(0..7)][f(0..63)][8 j's] bf16.
__global__ __launch_bounds__(256) void k_main(const float* __restrict__ x,
                                              const int* __restrict__ adj,
                                              const float* __restrict__ av,
                                              const __bf16* __restrict__ wtsw,
                                              __bf16* __restrict__ whtB32,
                                              float* __restrict__ f1T,
                                              float* __restrict__ f2pn,
                                              unsigned long long* __restrict__ bmT) {
    __shared__ alignas(16) __bf16 Bs[2][64 * 64];
    const int bid = blockIdx.x;
    const int t = threadIdx.x;
    if (bid < 512) {
        // ---- Wh = bf16(x) @ bf16(W) via 16x16x32 MFMA ----
        const int wv = t >> 6, l = t & 63;
        const int jt = bid & 63, h = bid >> 6;
        const int bm = jt * 64, bn = h * 64;
        const int lm = l & 15, lk = l >> 4;
        const int swB = (lm & 7) << 4;

        f32x4 acc[4] = {};
        auto stageB = [&](int kt, int bb) {
            #pragma unroll
            for (int kq = 0; kq < 2; ++kq) {
                int u = t + kq * 256;
                __builtin_amdgcn_global_load_lds(
                    (const __attribute__((address_space(1))) void*)(wtsw + (size_t)(kt * NFLAT + bn) * 64 + u * 8),
                    (__attribute__((address_space(3))) void*)((char*)&Bs[bb][0] + u * 16), 16, 0, 0);
            }
        };

        stageB(0, 0);
        const float* xrow = &x[(size_t)(bm + wv * 16 + lm) * FIN + lk * 8];
        for (int kt = 0; kt < 8; ++kt) {
            bf16x8 aF[2];
            #pragma unroll
            for (int ks = 0; ks < 2; ++ks) {
                float4 u0 = *(const float4*)&xrow[kt * 64 + ks * 32];
                float4 u1 = *(const float4*)&xrow[kt * 64 + ks * 32 + 4];
                bf16x8 af;
                af[0] = (__bf16)u0.x; af[1] = (__bf16)u0.y; af[2] = (__bf16)u0.z; af[3] = (__bf16)u0.w;
                af[4] = (__bf16)u1.x; af[5] = (__bf16)u1.y; af[6] = (__bf16)u1.z; af[7] = (__bf16)u1.w;
                aF[ks] = af;
            }
            __syncthreads();
            if (kt < 7) stageB(kt + 1, (kt + 1) & 1);
            const char* wb = (const char*)&Bs[kt & 1][0];
            #pragma unroll
            for (int q = 0; q < 4; ++q) {
                #pragma unroll
                for (int ks = 0; ks < 2; ++ks) {
                    bf16x8 bF = *(const bf16x8*)(wb + (((q * 16 + lm) * 128 + lk * 16 + ks * 64) ^ swB));
                    acc[q] = __builtin_amdgcn_mfma_f32_16x16x32_bf16(aF[ks], bF, acc[q], 0, 0, 0);
                }
            }
        }
        // ---- epilogue 1: whtB32 fragment-ordered store ----
        {
            char* blk = (char*)whtB32 + ((size_t)(h * 64 + jt) << 13);  // 8KB per (h,jt)
            const int jg = wv * 2 + (lk >> 1);
            const int j7o = (lk & 1) * 8;
            #pragma unroll
            for (int q = 0; q < 4; ++q) {
                const int f = q * 16 + lm;
                bf16x4 o;
                #pragma unroll
                for (int r = 0; r < 4; ++r) o[r] = (__bf16)acc[q][r];
                *(bf16x4*)(blk + (jg * 64 + f) * 16 + j7o) = o;
            }
        }
        // ---- epilogue 2: fused f12 ----
        float av1[4], av2[4];
        #pragma unroll
        for (int q = 0; q < 4; ++q) {
            av1[q] = av[q * 16 + lm];
            av2[q] = av[64 + q * 16 + lm];
        }
        float s1[4] = {}, s2[4] = {};
        #pragma unroll
        for (int q = 0; q < 4; ++q)
            #pragma unroll
            for (int r = 0; r < 4; ++r) {
                s1[r] = fmaf(acc[q][r], av1[q], s1[r]);
                s2[r] = fmaf(acc[q][r], av2[q], s2[r]);
            }
        #pragma unroll
        for (int off = 1; off < 16; off <<= 1) {
            #pragma unroll
            for (int r = 0; r < 4; ++r) {
                s1[r] += __shfl_xor(s1[r], off);
                s2[r] += __shfl_xor(s2[r], off);
            }
        }
        if (lm == 0) {
            #pragma unroll
            for (int r = 0; r < 4; ++r) {
                const int io = bm + wv * 16 + lk * 4 + r;
                f1T[h * NN + io] = s1[r] * LOG2E;
                float s2l = s2[r] * LOG2E;
                float2 v = make_float2(exp2f(s2l), exp2f(LRELU_ALPHA * s2l));
                *(float2*)&f2pn[2 * ((size_t)h * NN + io)] = v;
            }
        }
    } else {
        // ---- bitmask pack: adj -> bmT[jt*NN + i] ----
        const size_t base = (size_t)(bid - 512) * 16384;
        for (int it = 0; it < 64; ++it) {
            size_t idx = base + (size_t)it * 256 + t;
            int v = adj[idx];
            unsigned long long b = __ballot(v > 0);
            if ((t & 63) == 0) {
                int i = (int)(idx >> 12);
                int jt = (int)((idx >> 6) & 63);
                bmT[(size_t)jt * NN + i] = b;
            }
        }
    }
}

// ================= k_attn: R12 structure + XCD head-pinning (h = bid & 7) =================
// Block = 32 i x 1 head; wave wv owns j-tiles [wv*16, wv*16+16); per-wave 2x8KB dbuf,
// counted vmcnt(25); in-kernel cross-wave reduce + normalize; zero atomics.
__global__ __launch_bounds__(256, 2) void k_attn(const unsigned long long* __restrict__ bmT,
                                                 const __bf16* __restrict__ whtB32,
                                                 const float* __restrict__ f1T,
                                                 const float* __restrict__ f2pn,
                                                 float* __restrict__ oacc) {
    __shared__ alignas(16) char Ws[4][2][8192];    // per-wave private dbuf; reused as reduce buf

    const int t   = threadIdx.x;
    const int wv  = t >> 6, l = t & 63;
    const int h   = blockIdx.x & 7;                // XCD-pinned head (linear id % 8 -> XCD)
    const int gi0 = (blockIdx.x >> 3) * 32;        // 32 i-rows per block
    const int jt0 = wv * 16;                       // per-wave j-chunk (16 tiles)

    const int lc = l & 31, hi = l >> 5;
    const int iA = gi0 + lc;                       // all waves share the same 32 rows
    const float f1v = f1T[h * NN + iA];
    const float E1p = exp2f(f1v);
    const float E1n = exp2f(LRELU_ALPHA * f1v);

    f32x16 acc0 = {}, acc1 = {};
    float lpart = 0.f;

    // rolling pointers (one add per tile each)
    const char* gsrc = (const char*)whtB32 + ((size_t)(h * 64 + jt0) << 13) + l * 16;          // +8192/tile
    const char* fptr = (const char*)f2pn + ((size_t)h * NN + (size_t)jt0 * 64) * 8 + hi * 64;  // +512/tile
    const unsigned long long* mptr = bmT + (size_t)jt0 * NN + iA;                              // +NN/tile
    char* const wsA = &Ws[wv][0][0];
    char* const wsB = &Ws[wv][1][0];
    const int dsoff = (hi << 10) | (lc << 4);

    auto stage = [&](const char* src, char* dstbase) {
        #pragma unroll
        for (int k = 0; k < 8; ++k)
            __builtin_amdgcn_global_load_lds(
                (const __attribute__((address_space(1))) void*)(src + k * 1024),
                (__attribute__((address_space(3))) void*)(dstbase + l * 16 + k * 1024), 16, 0, 0);
    };
    auto loadF2 = [&](float4* F, const char* fp) {
        #pragma unroll
        for (int js = 0; js < 4; ++js)
            #pragma unroll
            for (int u = 0; u < 4; ++u)
                F[js * 4 + u] = *(const float4*)(fp + js * 128 + u * 16);
    };
    auto compute = [&](const char* wsb, const float4* F, unsigned long long m) {
        const unsigned long long ml = m >> (hi * 8);
        const char* bp = wsb + dsoff;
        #pragma unroll
        for (int js = 0; js < 4; ++js) {
            unsigned mk = (unsigned)(ml >> (16 * js));
            bf16x8 aF;
            #pragma unroll
            for (int u = 0; u < 4; ++u) {
                float4 vv = F[js * 4 + u];
                float a0 = fmaxf(E1p * vv.x, E1n * vv.y);
                float a1 = fmaxf(E1p * vv.z, E1n * vv.w);
                a0 = __uint_as_float(__float_as_uint(a0) & bitsmear(mk, 2 * u));
                a1 = __uint_as_float(__float_as_uint(a1) & bitsmear(mk, 2 * u + 1));
                lpart += a0 + a1;
                aF[2 * u]     = (__bf16)a0;
                aF[2 * u + 1] = (__bf16)a1;
            }
            bf16x8 bF0 = *(const bf16x8*)(bp + js * 2048);
            bf16x8 bF1 = *(const bf16x8*)(bp + js * 2048 + 512);
            __builtin_amdgcn_s_setprio(1);
            acc0 = __builtin_amdgcn_mfma_f32_32x32x16_bf16(aF, bF0, acc0, 0, 0, 0);
            acc1 = __builtin_amdgcn_mfma_f32_32x32x16_bf16(aF, bF1, acc1, 0, 0, 0);
            __builtin_amdgcn_s_setprio(0);
        }
    };

    float4 fA[16], fB[16];
    unsigned long long mA_, mB_;

    // prologue: tile jt0 -> buf A / fA / mA (25 loads, pinned order)
    stage(gsrc, wsA);
    __builtin_amdgcn_sched_barrier(0);
    loadF2(fA, fptr);
    mA_ = *mptr;
    __builtin_amdgcn_sched_barrier(0);
    gsrc += 8192; fptr += 512; mptr += NN;

    // NOTE: final-iteration prefetch overruns into adjacent d_ws regions (valid memory,
    // values never consumed).
    #pragma unroll 1
    for (int jj = 0; jj < 16; jj += 2) {
        stage(gsrc, wsB);
        __builtin_amdgcn_sched_barrier(0);
        loadF2(fB, fptr);
        mB_ = *mptr;
        __builtin_amdgcn_sched_barrier(0);
        gsrc += 8192; fptr += 512; mptr += NN;
        asm volatile("s_waitcnt vmcnt(25)" ::: "memory");   // keep the 25 next-tile loads in flight
        __builtin_amdgcn_sched_barrier(0);
        compute(wsA, fA, mA_);
        stage(gsrc, wsA);
        __builtin_amdgcn_sched_barrier(0);
        loadF2(fA, fptr);
        mA_ = *mptr;
        __builtin_amdgcn_sched_barrier(0);
        gsrc += 8192; fptr += 512; mptr += NN;
        asm volatile("s_waitcnt vmcnt(25)" ::: "memory");
        __builtin_amdgcn_sched_barrier(0);
        compute(wsB, fB, mB_);
    }

    // drain this wave's outstanding gload_lds before reusing its buffers for the reduction
    asm volatile("s_waitcnt vmcnt(0)" ::: "memory");
    __builtin_amdgcn_sched_barrier(0);

    // ---- write partials into own (dead) staging buffers ----
    {
        float* Rp = (float*)wsA;                   // 32 rows x 64 cols f32 = 8KB
        float* Lp = (float*)wsB;                   // 2x32 row-sum slices
        #pragma unroll
        for (int reg = 0; reg < 16; ++reg) {
            const int row = (reg & 3) + 8 * (reg >> 2) + 4 * hi;
            Rp[row * 64 + lc]      = acc0[reg];
            Rp[row * 64 + 32 + lc] = acc1[reg];
        }
        Lp[hi * 32 + lc] = lpart;
    }
    __syncthreads();

    // ---- cross-wave reduce + normalize + plain store (no atomics) ----
    {
        const int row = t >> 3, c0 = (t & 7) * 8;
        float ls = 0.f;
        #pragma unroll
        for (int w2 = 0; w2 < 4; ++w2) {
            const float* Lp2 = (const float*)&Ws[w2][1][0];
            ls += Lp2[row] + Lp2[32 + row];
        }
        const float inv = 1.0f / (ls * (float)NH);
        f32x4 s0 = {}, s1 = {};
        #pragma unroll
        for (int w2 = 0; w2 < 4; ++w2) {
            const float* Rp2 = (const float*)&Ws[w2][0][0];
            s0 += *(const f32x4*)&Rp2[row * 64 + c0];
            s1 += *(const f32x4*)&Rp2[row * 64 + c0 + 4];
        }
        float* dst = &oacc[(size_t)(gi0 + row) * NFLAT + h * 64 + c0];
        *(f32x4*)dst       = s0 * inv;
        *(f32x4*)(dst + 4) = s1 * inv;
    }
}

// ================= k_norm: head-sum only (oacc already normalized) =================
__global__ __launch_bounds__(256) void k_norm(const float* __restrict__ oacc,
                                              float* __restrict__ out) {
    int t = blockIdx.x * 256 + threadIdx.x;
    int i = t >> 4, fq = (t & 15) * 4;
    f32x4 s = {};
    #pragma unroll
    for (int h = 0; h < 8; ++h)
        s += *(const f32x4*)&oacc[(size_t)i * NFLAT + h * 64 + fq];
    *(f32x4*)&out[(size_t)i * FOUT + fq] = s;
}

extern "C" void kernel_launch(void* const* d_in, const int* in_sizes, int n_in,
                              void* d_out, int out_size, void* d_ws, size_t ws_size,
                              hipStream_t stream) {
    const float* x   = (const float*)d_in[0];
    const int*   adj = (const int*)d_in[1];
    const float* W   = (const float*)d_in[2];
    const float* a   = (const float*)d_in[3];
    float* out = (float*)d_out;

    char* ws = (char*)d_ws;
    float* oacc = (float*)ws;           ws += (size_t)NN * NFLAT * 4;   // 8 MiB
    float* f1T = (float*)ws;            ws += (size_t)NH * NN * 4;      // 128 KiB
    float* f2pn = (float*)ws;           ws += (size_t)NH * NN * 8;      // 256 KiB
    __bf16* whtB32 = (__bf16*)ws;       ws += (size_t)NFLAT * NN * 2;   // 4 MiB
    unsigned long long* bmT = (unsigned long long*)ws; ws += (size_t)NN * NN / 8; // 2 MiB
    __bf16* wtsw = (__bf16*)ws;         ws += (size_t)FIN * NFLAT * 2;  // 512 KiB

    k_prep<<<64, 256, 0, stream>>>(W, wtsw);
    k_main<<<1536, 256, 0, stream>>>(x, adj, a, wtsw, whtB32, f1T, f2pn, bmT);
    k_attn<<<1024, 256, 0, stream>>>(bmT, whtB32, f1T, f2pn, oacc);
    k_norm<<<NN * FOUT / 4 / 256, 256, 0, stream>>>(oacc, out);
}

// Round 16
// 89.400 us; speedup vs baseline: 1.6190x; 1.1453x over previous
//
#include <hip/hip_runtime.h>

#define LRELU_ALPHA 0.2f

constexpr int NN    = 4096;
constexpr int FIN   = 512;
constexpr int NH    = 8;
constexpr int FOUT  = 64;
constexpr int NFLAT = NH * FOUT; // 512
constexpr float LOG2E = 1.4426950408889634f;

typedef __attribute__((ext_vector_type(8))) __bf16 bf16x8;
typedef __attribute__((ext_vector_type(4))) float f32x4;
typedef __attribute__((ext_vector_type(16))) float f32x16;
typedef _Float16 f16;
typedef __attribute__((ext_vector_type(2))) _Float16 f16x2;
typedef __attribute__((ext_vector_type(4))) _Float16 f16x4;
typedef __attribute__((ext_vector_type(8))) _Float16 f16x8;

__device__ __forceinline__ unsigned bitsmear(unsigned mk, int e) {
    return (unsigned)(((int)(mk << (31 - e))) >> 31);   // bit e -> 0 / 0xFFFFFFFF (v_bfe_i32)
}

// ================= k_prep: W -> wtsw (bf16, pre-swizzled for k_main's gload_lds) =========
__global__ __launch_bounds__(256) void k_prep(const float* __restrict__ W,
                                              __bf16* __restrict__ wtsw) {
    __shared__ float tile[64][68];
    const int bid = blockIdx.x;
    const int t = threadIdx.x;
    const int kt = bid >> 3;
    const int fb = (bid & 7) * 64;
    {
        const int kk = t >> 2, cq = (t & 3) * 16;
        #pragma unroll
        for (int i = 0; i < 4; ++i)
            *(float4*)&tile[kk][cq + i * 4] =
                *(const float4*)&W[(size_t)(kt * 64 + kk) * NFLAT + fb + cq + i * 4];
    }
    __syncthreads();
    const int fl = t >> 2;
    #pragma unroll
    for (int c = 0; c < 2; ++c) {
        int gs = (t & 3) * 2 + c;
        int g  = gs ^ (fl & 7);
        bf16x8 o;
        #pragma unroll
        for (int jo = 0; jo < 8; ++jo) o[jo] = (__bf16)tile[g * 8 + jo][fl];
        *(bf16x8*)&wtsw[((size_t)(kt * NFLAT + fb + fl)) * 64 + gs * 8] = o;
    }
}

// ================= k_main: gemm(->whtB16 f16 fragment order, fused f12) + bitmask =========
// whtB16 per (h,jt) 8KB block: [jg(0..7)][f(0..63)][8 j's] f16.
// f2pk: packed f16 pair streams. P-pair(j/2) at f2pk[h*NN/2 + j/2]; N at +NH*NN/2.
__global__ __launch_bounds__(256) void k_main(const float* __restrict__ x,
                                              const int* __restrict__ adj,
                                              const float* __restrict__ av,
                                              const __bf16* __restrict__ wtsw,
                                              f16* __restrict__ whtB16,
                                              float* __restrict__ f1T,
                                              unsigned* __restrict__ f2pk,
                                              unsigned long long* __restrict__ bmT) {
    __shared__ alignas(16) __bf16 Bs[2][64 * 64];
    const int bid = blockIdx.x;
    const int t = threadIdx.x;
    if (bid < 512) {
        // ---- Wh = bf16(x) @ bf16(W) via 16x16x32 MFMA ----
        const int wv = t >> 6, l = t & 63;
        const int jt = bid & 63, h = bid >> 6;
        const int bm = jt * 64, bn = h * 64;
        const int lm = l & 15, lk = l >> 4;
        const int swB = (lm & 7) << 4;

        f32x4 acc[4] = {};
        auto stageB = [&](int kt, int bb) {
            #pragma unroll
            for (int kq = 0; kq < 2; ++kq) {
                int u = t + kq * 256;
                __builtin_amdgcn_global_load_lds(
                    (const __attribute__((address_space(1))) void*)(wtsw + (size_t)(kt * NFLAT + bn) * 64 + u * 8),
                    (__attribute__((address_space(3))) void*)((char*)&Bs[bb][0] + u * 16), 16, 0, 0);
            }
        };

        stageB(0, 0);
        const float* xrow = &x[(size_t)(bm + wv * 16 + lm) * FIN + lk * 8];
        for (int kt = 0; kt < 8; ++kt) {
            bf16x8 aF[2];
            #pragma unroll
            for (int ks = 0; ks < 2; ++ks) {
                float4 u0 = *(const float4*)&xrow[kt * 64 + ks * 32];
                float4 u1 = *(const float4*)&xrow[kt * 64 + ks * 32 + 4];
                bf16x8 af;
                af[0] = (__bf16)u0.x; af[1] = (__bf16)u0.y; af[2] = (__bf16)u0.z; af[3] = (__bf16)u0.w;
                af[4] = (__bf16)u1.x; af[5] = (__bf16)u1.y; af[6] = (__bf16)u1.z; af[7] = (__bf16)u1.w;
                aF[ks] = af;
            }
            __syncthreads();
            if (kt < 7) stageB(kt + 1, (kt + 1) & 1);
            const char* wb = (const char*)&Bs[kt & 1][0];
            #pragma unroll
            for (int q = 0; q < 4; ++q) {
                #pragma unroll
                for (int ks = 0; ks < 2; ++ks) {
                    bf16x8 bF = *(const bf16x8*)(wb + (((q * 16 + lm) * 128 + lk * 16 + ks * 64) ^ swB));
                    acc[q] = __builtin_amdgcn_mfma_f32_16x16x32_bf16(aF[ks], bF, acc[q], 0, 0, 0);
                }
            }
        }
        // ---- epilogue 1: whtB16 fragment-ordered store (f16) ----
        {
            char* blk = (char*)whtB16 + ((size_t)(h * 64 + jt) << 13);  // 8KB per (h,jt)
            const int jg = wv * 2 + (lk >> 1);
            const int j7o = (lk & 1) * 8;
            #pragma unroll
            for (int q = 0; q < 4; ++q) {
                const int f = q * 16 + lm;
                f16x4 o;
                #pragma unroll
                for (int r = 0; r < 4; ++r) o[r] = (f16)acc[q][r];
                *(f16x4*)(blk + (jg * 64 + f) * 16 + j7o) = o;
            }
        }
        // ---- epilogue 2: fused f12 (f1 f32*log2e; f2 -> packed f16 exp2 pair streams) ----
        float av1[4], av2[4];
        #pragma unroll
        for (int q = 0; q < 4; ++q) {
            av1[q] = av[q * 16 + lm];
            av2[q] = av[64 + q * 16 + lm];
        }
        float s1[4] = {}, s2[4] = {};
        #pragma unroll
        for (int q = 0; q < 4; ++q)
            #pragma unroll
            for (int r = 0; r < 4; ++r) {
                s1[r] = fmaf(acc[q][r], av1[q], s1[r]);
                s2[r] = fmaf(acc[q][r], av2[q], s2[r]);
            }
        #pragma unroll
        for (int off = 1; off < 16; off <<= 1) {
            #pragma unroll
            for (int r = 0; r < 4; ++r) {
                s1[r] += __shfl_xor(s1[r], off);
                s2[r] += __shfl_xor(s2[r], off);
            }
        }
        if (lm == 0) {
            float p[4], n[4];
            #pragma unroll
            for (int r = 0; r < 4; ++r) {
                const int io = bm + wv * 16 + lk * 4 + r;
                f1T[h * NN + io] = s1[r] * LOG2E;
                float s2l = s2[r] * LOG2E;
                p[r] = exp2f(s2l);
                n[r] = exp2f(LRELU_ALPHA * s2l);
            }
            const int io0 = bm + wv * 16 + lk * 4;
            f16x2 P01 = {(f16)p[0], (f16)p[1]}, P23 = {(f16)p[2], (f16)p[3]};
            f16x2 N01 = {(f16)n[0], (f16)n[1]}, N23 = {(f16)n[2], (f16)n[3]};
            uint2 Pv = {__builtin_bit_cast(unsigned, P01), __builtin_bit_cast(unsigned, P23)};
            uint2 Nv = {__builtin_bit_cast(unsigned, N01), __builtin_bit_cast(unsigned, N23)};
            *(uint2*)&f2pk[(h * NN + io0) >> 1] = Pv;
            *(uint2*)&f2pk[(NH * NN / 2) + ((h * NN + io0) >> 1)] = Nv;
        }
    } else {
        // ---- bitmask pack: adj -> bmT[jt*NN + i] ----
        const size_t base = (size_t)(bid - 512) * 16384;
        for (int it = 0; it < 64; ++it) {
            size_t idx = base + (size_t)it * 256 + t;
            int v = adj[idx];
            unsigned long long b = __ballot(v > 0);
            if ((t & 63) == 0) {
                int i = (int)(idx >> 12);
                int jt = (int)((idx >> 6) & 63);
                bmT[(size_t)jt * NN + i] = b;
            }
        }
    }
}

// ================= k_attn: R12 structure, fp16 packed P-math, f16 MFMA ====================
// Block = 32 i x 1 head (h = bid&7, XCD-pinned); wave wv owns j-tiles [wv*16, wv*16+16);
// per-wave 2x8KB dbuf, counted vmcnt(17); in-kernel reduce+normalize; zero atomics.
__global__ __launch_bounds__(256, 2) void k_attn(const unsigned long long* __restrict__ bmT,
                                                 const f16* __restrict__ whtB16,
                                                 const float* __restrict__ f1T,
                                                 const unsigned* __restrict__ f2pk,
                                                 float* __restrict__ oacc) {
    __shared__ alignas(16) char Ws[4][2][8192];    // per-wave private dbuf; reused as reduce buf

    const int t   = threadIdx.x;
    const int wv  = t >> 6, l = t & 63;
    const int h   = blockIdx.x & 7;                // XCD-pinned head
    const int gi0 = (blockIdx.x >> 3) * 32;        // 32 i-rows per block
    const int jt0 = wv * 16;                       // per-wave j-chunk (16 tiles)

    const int lc = l & 31, hi = l >> 5;
    const int iA = gi0 + lc;
    const float f1v = f1T[h * NN + iA];
    const float E1pf = exp2f(f1v);
    const float E1nf = exp2f(LRELU_ALPHA * f1v);
    const f16x2 e1p2 = {(f16)E1pf, (f16)E1pf};
    const f16x2 e1n2 = {(f16)E1nf, (f16)E1nf};
    const f16x2 one2 = {(f16)1.0f, (f16)1.0f};

    f32x16 acc0 = {}, acc1 = {};
    float lpart = 0.f;

    // rolling pointers (one add per tile each)
    const char* gsrc = (const char*)whtB16 + ((size_t)(h * 64 + jt0) << 13) + l * 16;   // +8192/tile
    const char* fptr = (const char*)f2pk + (size_t)h * NN * 2 + jt0 * 128 + hi * 16;    // +128/tile
    const unsigned long long* mptr = bmT + (size_t)jt0 * NN + iA;                       // +NN/tile
    constexpr int NOFF = NH * NN * 2;              // byte distance P-stream -> N-stream
    char* const wsA = &Ws[wv][0][0];
    char* const wsB = &Ws[wv][1][0];
    const int dsoff = (hi << 10) | (lc << 4);

    auto stage = [&](const char* src, char* dstbase) {       // 8 loads
        #pragma unroll
        for (int k = 0; k < 8; ++k)
            __builtin_amdgcn_global_load_lds(
                (const __attribute__((address_space(1))) void*)(src + k * 1024),
                (__attribute__((address_space(3))) void*)(dstbase + l * 16 + k * 1024), 16, 0, 0);
    };
    auto loadF2 = [&](uint4* FP, uint4* FN, const char* fp) { // 8 loads
        #pragma unroll
        for (int js = 0; js < 4; ++js) {
            FP[js] = *(const uint4*)(fp + js * 32);
            FN[js] = *(const uint4*)(fp + NOFF + js * 32);
        }
    };
    auto compute = [&](const char* wsb, const uint4* FP, const uint4* FN, unsigned long long m) {
        const unsigned long long ml = m >> (hi * 8);
        const char* bp = wsb + dsoff;
        #pragma unroll
        for (int js = 0; js < 4; ++js) {
            unsigned mk = (unsigned)(ml >> (16 * js));
            const uint4 P4 = FP[js], N4 = FN[js];
            unsigned r[4];
            #pragma unroll
            for (int u = 0; u < 4; ++u) {
                unsigned pu = (&P4.x)[u], nu = (&N4.x)[u];
                f16x2 a = e1p2 * __builtin_bit_cast(f16x2, pu);
                f16x2 b = e1n2 * __builtin_bit_cast(f16x2, nu);
                f16x2 mx = __builtin_elementwise_max(a, b);
                unsigned t0 = bitsmear(mk, 2 * u), t1 = bitsmear(mk, 2 * u + 1);
                unsigned msk = (t0 & 0x0000FFFFu) | (t1 & 0xFFFF0000u);   // v_bfi
                unsigned rv = __builtin_bit_cast(unsigned, mx) & msk;
                r[u] = rv;
                lpart = __builtin_amdgcn_fdot2(__builtin_bit_cast(f16x2, rv), one2, lpart, false);
            }
            uint4 ru = {r[0], r[1], r[2], r[3]};
            f16x8 aF = __builtin_bit_cast(f16x8, ru);
            f16x8 bF0 = *(const f16x8*)(bp + js * 2048);
            f16x8 bF1 = *(const f16x8*)(bp + js * 2048 + 512);
            __builtin_amdgcn_s_setprio(1);
            acc0 = __builtin_amdgcn_mfma_f32_32x32x16_f16(aF, bF0, acc0, 0, 0, 0);
            acc1 = __builtin_amdgcn_mfma_f32_32x32x16_f16(aF, bF1, acc1, 0, 0, 0);
            __builtin_amdgcn_s_setprio(0);
        }
    };

    uint4 fAP[4], fAN[4], fBP[4], fBN[4];
    unsigned long long mA_, mB_;

    // prologue: tile jt0 -> buf A / fA / mA (17 loads, pinned order)
    stage(gsrc, wsA);
    __builtin_amdgcn_sched_barrier(0);
    loadF2(fAP, fAN, fptr);
    mA_ = *mptr;
    __builtin_amdgcn_sched_barrier(0);
    gsrc += 8192; fptr += 128; mptr += NN;

    // NOTE: final-iteration prefetch overruns into adjacent d_ws regions (valid memory,
    // values never consumed).
    #pragma unroll 1
    for (int jj = 0; jj < 16; jj += 2) {
        stage(gsrc, wsB);
        __builtin_amdgcn_sched_barrier(0);
        loadF2(fBP, fBN, fptr);
        mB_ = *mptr;
        __builtin_amdgcn_sched_barrier(0);
        gsrc += 8192; fptr += 128; mptr += NN;
        asm volatile("s_waitcnt vmcnt(17)" ::: "memory");   // keep the 17 next-tile loads in flight
        __builtin_amdgcn_sched_barrier(0);
        compute(wsA, fAP, fAN, mA_);
        stage(gsrc, wsA);
        __builtin_amdgcn_sched_barrier(0);
        loadF2(fAP, fAN, fptr);
        mA_ = *mptr;
        __builtin_amdgcn_sched_barrier(0);
        gsrc += 8192; fptr += 128; mptr += NN;
        asm volatile("s_waitcnt vmcnt(17)" ::: "memory");
        __builtin_amdgcn_sched_barrier(0);
        compute(wsB, fBP, fBN, mB_);
    }

    // drain this wave's outstanding gload_lds before reusing its buffers for the reduction
    asm volatile("s_waitcnt vmcnt(0)" ::: "memory");
    __builtin_amdgcn_sched_barrier(0);

    // ---- write partials into own (dead) staging buffers ----
    {
        float* Rp = (float*)wsA;                   // 32 rows x 64 cols f32 = 8KB
        float* Lp = (float*)wsB;                   // 2x32 row-sum slices
        #pragma unroll
        for (int reg = 0; reg < 16; ++reg) {
            const int row = (reg & 3) + 8 * (reg >> 2) + 4 * hi;
            Rp[row * 64 + lc]      = acc0[reg];
            Rp[row * 64 + 32 + lc] = acc1[reg];
        }
        Lp[hi * 32 + lc] = lpart;
    }
    __syncthreads();

    // ---- cross-wave reduce + normalize + plain store (no atomics) ----
    {
        const int row = t >> 3, c0 = (t & 7) * 8;
        float ls = 0.f;
        #pragma unroll
        for (int w2 = 0; w2 < 4; ++w2) {
            const float* Lp2 = (const float*)&Ws[w2][1][0];
            ls += Lp2[row] + Lp2[32 + row];
        }
        const float inv = 1.0f / (ls * (float)NH);
        f32x4 s0 = {}, s1 = {};
        #pragma unroll
        for (int w2 = 0; w2 < 4; ++w2) {
            const float* Rp2 = (const float*)&Ws[w2][0][0];
            s0 += *(const f32x4*)&Rp2[row * 64 + c0];
            s1 += *(const f32x4*)&Rp2[row * 64 + c0 + 4];
        }
        float* dst = &oacc[(size_t)(gi0 + row) * NFLAT + h * 64 + c0];
        *(f32x4*)dst       = s0 * inv;
        *(f32x4*)(dst + 4) = s1 * inv;
    }
}

// ================= k_norm: head-sum only (oacc already normalized) =================
__global__ __launch_bounds__(256) void k_norm(const float* __restrict__ oacc,
                                              float* __restrict__ out) {
    int t = blockIdx.x * 256 + threadIdx.x;
    int i = t >> 4, fq = (t & 15) * 4;
    f32x4 s = {};
    #pragma unroll
    for (int h = 0; h < 8; ++h)
        s += *(const f32x4*)&oacc[(size_t)i * NFLAT + h * 64 + fq];
    *(f32x4*)&out[(size_t)i * FOUT + fq] = s;
}

extern "C" void kernel_launch(void* const* d_in, const int* in_sizes, int n_in,
                              void* d_out, int out_size, void* d_ws, size_t ws_size,
                              hipStream_t stream) {
    const float* x   = (const float*)d_in[0];
    const int*   adj = (const int*)d_in[1];
    const float* W   = (const float*)d_in[2];
    const float* a   = (const float*)d_in[3];
    float* out = (float*)d_out;

    char* ws = (char*)d_ws;
    float* oacc = (float*)ws;           ws += (size_t)NN * NFLAT * 4;   // 8 MiB
    float* f1T = (float*)ws;            ws += (size_t)NH * NN * 4;      // 128 KiB
    unsigned* f2pk = (unsigned*)ws;     ws += (size_t)192 * 1024;       // 128 KiB + overrun slack
    f16* whtB16 = (f16*)ws;             ws += (size_t)NFLAT * NN * 2;   // 4 MiB
    unsigned long long* bmT = (unsigned long long*)ws; ws += (size_t)NN * NN / 8; // 2 MiB
    __bf16* wtsw = (__bf16*)ws;         ws += (size_t)FIN * NFLAT * 2;  // 512 KiB

    k_prep<<<64, 256, 0, stream>>>(W, wtsw);
    k_main<<<1536, 256, 0, stream>>>(x, adj, a, wtsw, whtB16, f1T, f2pk, bmT);
    k_attn<<<1024, 256, 0, stream>>>(bmT, whtB16, f1T, f2pk, oacc);
    k_norm<<<NN * FOUT / 4 / 256, 256, 0, stream>>>(oacc, out);
}